// Round 7
// baseline (158.279 us; speedup 1.0000x reference)
//
#include <hip/hip_runtime.h>

#define SL 10
#define NI 128
#define NCW 8   // compute waves (16 rows each)
#define NLW 2   // loader waves (64 rows each)

typedef float f32x4 __attribute__((ext_vector_type(4)));
typedef unsigned int u32;
typedef u32 u32x4 __attribute__((ext_vector_type(4)));
typedef _Float16 h8 __attribute__((ext_vector_type(8)));
typedef _Float16 h4 __attribute__((ext_vector_type(4)));

__device__ __forceinline__ f32x4 MFH(h8 a, h8 b, f32x4 c){
  return __builtin_amdgcn_mfma_f32_16x16x32_f16(a, b, c, 0, 0, 0);
}
__device__ __forceinline__ float sigf(float x){ return __fdividef(1.f, 1.f + __expf(-x)); }
__device__ __forceinline__ float tanhf2(float x){ return __fdividef(2.f, 1.f + __expf(-2.f*x)) - 1.f; }

__device__ __forceinline__ h8 to_h8(float4 a, float4 b){
  h8 r;
  r[0]=(_Float16)a.x; r[1]=(_Float16)a.y; r[2]=(_Float16)a.z; r[3]=(_Float16)a.w;
  r[4]=(_Float16)b.x; r[5]=(_Float16)b.y; r[6]=(_Float16)b.z; r[7]=(_Float16)b.w;
  return r;
}

// Producer/consumer persistent blocks: 640 thr = 2 loader waves + 8 compute waves,
// 128 batch rows/block, grid 256 = 1 block/CU.
//   Loaders: fully-coalesced 1KB spans (2 rows x 512B per instr), f32->f16,
//   depth-3 LDS ring XB[3][128 rows][256B] with XOR swizzle (byte ^ (row&7)<<4),
//   running 2 steps ahead of compute; never wait on consumers.
//   Compute (per wave, 16 rows): r3 structure — A = gate-permuted weights
//   (tile nt, A-row lr -> gate (lr&3)*20+(lr>>2)+nt*4), B = x/h fragments,
//   C-reg i of lane (lr,lg) = gate type i of unit nt*4+lg -> in-register fp32
//   gates; h 2-term f16 via wave-private HB (stride 33).
//   1 block-wide barrier per timestep (10 total each path).
__global__ __launch_bounds__(640, 3) void bilstm_kernel(
    const float* __restrict__ x,
    const float* __restrict__ Wih_f, const float* __restrict__ Whh_f,
    const float* __restrict__ bih_f, const float* __restrict__ bhh_f,
    const float* __restrict__ Wih_b,
    const float* __restrict__ bih_b, const float* __restrict__ bhh_b,
    float* __restrict__ out)
{
  __shared__ __attribute__((aligned(16))) char XB[3][128*256];  // 96 KB ring
  __shared__ u32 HBa[NCW][16*33];                               // 16.5 KB h-exchange

  const int tid  = threadIdx.x;
  const int ww   = tid >> 6;
  const int lane = tid & 63;
  const long b0  = (long)blockIdx.x * 128;

  if(ww >= NCW){
    // ================= loader wave =================
    const int w   = ww - NCW;          // 0,1
    const int rr  = lane >> 5;         // row within pair
    const int cc  = lane & 31;         // 16B segment (512B row span)
    const int wr0 = w*64 + rr;
    const float* lsrc = x + (b0 + wr0)*(long)(SL*NI) + cc*4;

    float4 lb[32];
    // issue t=0
    #pragma unroll
    for(int i=0;i<32;i++) lb[i] = *(const float4*)(lsrc + (long)2*i*SL*NI);
    // stage t=0 into XB[0]
    #pragma unroll
    for(int i=0;i<32;i++){
      float4 v = lb[i];
      h4 hv; hv[0]=(_Float16)v.x; hv[1]=(_Float16)v.y; hv[2]=(_Float16)v.z; hv[3]=(_Float16)v.w;
      const int r = wr0 + 2*i;
      *(h4*)(XB[0] + r*256 + ((cc*8) ^ ((r&7)<<4))) = hv;
    }
    // issue t=1
    #pragma unroll
    for(int i=0;i<32;i++) lb[i] = *(const float4*)(lsrc + NI + (long)2*i*SL*NI);
    __syncthreads();                       // barrier 0: buf0 (x_0) ready
    #pragma unroll
    for(int t=0;t<SL-1;t++){
      // stage x_{t+1} into XB[(t+1)%3] (waits on loads issued last iter)
      char* dst = XB[(t+1)%3];
      #pragma unroll
      for(int i=0;i<32;i++){
        float4 v = lb[i];
        h4 hv; hv[0]=(_Float16)v.x; hv[1]=(_Float16)v.y; hv[2]=(_Float16)v.z; hv[3]=(_Float16)v.w;
        const int r = wr0 + 2*i;
        *(h4*)(dst + r*256 + ((cc*8) ^ ((r&7)<<4))) = hv;
      }
      // issue x_{t+2} (2 steps ahead of consumers)
      if(t+2<SL){
        #pragma unroll
        for(int i=0;i<32;i++) lb[i] = *(const float4*)(lsrc + (t+2)*NI + (long)2*i*SL*NI);
      }
      __syncthreads();                     // barriers 1..9
    }
    return;                                // loaders exit; no further barriers anywhere
  }

  // ================= compute wave =================
  const int lr  = lane & 15;
  const int lg  = lane >> 4;
  const int gb  = (lr&3)*20 + (lr>>2);
  const long brow = b0 + ww*16 + lr;       // this lane's batch row (output col)
  const int rsw = (lr&7)<<4;               // read-side swizzle
  const int xoff = (ww*16 + lr)*256;       // row base in XB
  u32* HB = HBa[ww];

  for(int i=lane;i<16*33;i+=64) HB[i]=0;

  // W_ih_f fragments (f16), register-resident
  h8 WIH[20];
  #pragma unroll
  for(int p=0;p<20;p++){
    const int nt=p>>2, ks=p&3;
    const float* s = Wih_f + (gb+nt*4)*NI + ks*32 + lg*8;
    WIH[p] = to_h8(*(const float4*)s, *(const float4*)(s+4));
  }
  // W_hh_f fragments (K=20 zero-padded to 32)
  h8 WHH[5];
  #pragma unroll
  for(int nt=0;nt<5;nt++){
    h8 r;
    #pragma unroll
    for(int j=0;j<8;j++){
      const int k = lg*8+j;
      r[j] = (_Float16)((k<20) ? Whh_f[(gb+nt*4)*20+k] : 0.f);
    }
    WHH[nt]=r;
  }
  // forward bias, packed f16
  h4 bp[5];
  #pragma unroll
  for(int nt=0;nt<5;nt++)
    #pragma unroll
    for(int ty=0;ty<4;ty++)
      bp[nt][ty] = (_Float16)(bih_f[ty*20+nt*4+lg] + bhh_f[ty*20+nt*4+lg]);

  float cst[5]={0.f,0.f,0.f,0.f,0.f};
  f32x4 acc[5];

  __syncthreads();                         // barrier 0: x_0 staged
  #pragma unroll
  for(int t=0;t<SL;t++){
    const char* rb = XB[t%3] + xoff;
    // h_{t-1} read (own-wave LDS)
    u32x4 hb0, hb1;
    if(t>0){
      const u32* hp = HB + lr*33 + lg*8;
      hb0=*(const u32x4*)hp; hb1=*(const u32x4*)(hp+4);
    }
    #pragma unroll
    for(int nt=0;nt<5;nt++){
      acc[nt][0]=(float)bp[nt][0]; acc[nt][1]=(float)bp[nt][1];
      acc[nt][2]=(float)bp[nt][2]; acc[nt][3]=(float)bp[nt][3];
    }
    // projection: 20 MFMAs, B-frags streamed from LDS ring
    #pragma unroll
    for(int ks=0;ks<4;ks++){
      h8 bx = *(const h8*)(rb + ((ks*64 + lg*16) ^ rsw));
      #pragma unroll
      for(int nt=0;nt<5;nt++)
        acc[nt]=MFH(WIH[nt*4+ks], bx, acc[nt]);
    }
    // recurrence: 10 MFMAs (h 2-term f16)
    if(t>0){
      u32x4 hh, hl;
      hh[0]=(hb0[0]>>16)|(hb0[1]&0xffff0000u);
      hh[1]=(hb0[2]>>16)|(hb0[3]&0xffff0000u);
      hh[2]=(hb1[0]>>16)|(hb1[1]&0xffff0000u);
      hh[3]=(hb1[2]>>16)|(hb1[3]&0xffff0000u);
      hl[0]=(hb0[0]&0xffffu)|(hb0[1]<<16);
      hl[1]=(hb0[2]&0xffffu)|(hb0[3]<<16);
      hl[2]=(hb1[0]&0xffffu)|(hb1[1]<<16);
      hl[3]=(hb1[2]&0xffffu)|(hb1[3]<<16);
      h8 fh=__builtin_bit_cast(h8,hh), fl=__builtin_bit_cast(h8,hl);
      #pragma unroll
      for(int nt=0;nt<5;nt++){
        acc[nt]=MFH(WHH[nt], fh, acc[nt]);
        acc[nt]=MFH(WHH[nt], fl, acc[nt]);
      }
    }
    // in-register fp32 gate math
    #pragma unroll
    for(int nt=0;nt<5;nt++){
      float ig=sigf(acc[nt][0]);
      float fg=sigf(acc[nt][1]);
      float gg=tanhf2(acc[nt][2]);
      float og=sigf(acc[nt][3]);
      cst[nt]=fg*cst[nt]+ig*gg;
      float hv=og*tanhf2(cst[nt]);
      if(t==SL-1){
        out[brow*40 + nt*4+lg] = hv;
      } else {
        _Float16 hh16=(_Float16)hv;
        _Float16 hl16=(_Float16)(hv-(float)hh16);
        HB[lr*33 + nt*4+lg] = ((u32)__builtin_bit_cast(unsigned short,hh16)<<16)
                              | (u32)__builtin_bit_cast(unsigned short,hl16);
      }
    }
    if(t<SL-1) __syncthreads();            // barriers 1..9
  }

  // ---- backward direction: one step, h0=c0=0; x_9 frags still in XB[0] ----
  const char* rb9 = XB[(SL-1)%3] + xoff;
  f32x4 a2[5];
  #pragma unroll
  for(int nt=0;nt<5;nt++)
    #pragma unroll
    for(int ty=0;ty<4;ty++)
      a2[nt][ty] = bih_b[ty*20+nt*4+lg] + bhh_b[ty*20+nt*4+lg];
  #pragma unroll
  for(int ks=0;ks<4;ks++){
    h8 bx = *(const h8*)(rb9 + ((ks*64 + lg*16) ^ rsw));
    #pragma unroll
    for(int nt=0;nt<5;nt++){
      const float* s = Wih_b + (gb+nt*4)*NI + ks*32 + lg*8;
      a2[nt]=MFH(to_h8(*(const float4*)s, *(const float4*)(s+4)), bx, a2[nt]);
    }
  }
  #pragma unroll
  for(int nt=0;nt<5;nt++){
    float ig=sigf(a2[nt][0]);
    float gg=tanhf2(a2[nt][2]);
    float og=sigf(a2[nt][3]);
    out[brow*40 + 20 + nt*4+lg] = og*tanhf2(ig*gg);   // c = i*g (f-gate hits c0=0)
  }
}

extern "C" void kernel_launch(void* const* d_in, const int* in_sizes, int n_in,
                              void* d_out, int out_size, void* d_ws, size_t ws_size,
                              hipStream_t stream) {
  const float* x     = (const float*)d_in[0];
  const float* Wih_f = (const float*)d_in[1];
  const float* Whh_f = (const float*)d_in[2];
  const float* bih_f = (const float*)d_in[3];
  const float* bhh_f = (const float*)d_in[4];
  const float* Wih_b = (const float*)d_in[5];
  // d_in[6] = W_hh_b: provably unused (hs_b[0] has h0 = 0)
  const float* bih_b = (const float*)d_in[7];
  const float* bhh_b = (const float*)d_in[8];
  float* out = (float*)d_out;
  bilstm_kernel<<<dim3(256), dim3(640), 0, stream>>>(
      x, Wih_f, Whh_f, bih_f, bhh_f, Wih_b, bih_b, bhh_b, out);
}

// Round 8
// 113.022 us; speedup vs baseline: 1.4004x; 1.4004x over previous
//
#include <hip/hip_runtime.h>

#define SL 10
#define NI 128
#define NCW 4      // compute waves per block (16 rows each)
#define ROWS 64    // batch rows per block

typedef float f32x4 __attribute__((ext_vector_type(4)));
typedef unsigned int u32;
typedef u32 u32x4 __attribute__((ext_vector_type(4)));
typedef _Float16 h8 __attribute__((ext_vector_type(8)));
typedef _Float16 h4 __attribute__((ext_vector_type(4)));

__device__ __forceinline__ f32x4 MFH(h8 a, h8 b, f32x4 c){
  return __builtin_amdgcn_mfma_f32_16x16x32_f16(a, b, c, 0, 0, 0);
}
__device__ __forceinline__ float sigf(float x){ return __fdividef(1.f, 1.f + __expf(-x)); }
__device__ __forceinline__ float tanhf2(float x){ return __fdividef(2.f, 1.f + __expf(-2.f*x)) - 1.f; }

__device__ __forceinline__ h8 to_h8(float4 a, float4 b){
  h8 r;
  r[0]=(_Float16)a.x; r[1]=(_Float16)a.y; r[2]=(_Float16)a.z; r[3]=(_Float16)a.w;
  r[4]=(_Float16)b.x; r[5]=(_Float16)b.y; r[6]=(_Float16)b.z; r[7]=(_Float16)b.w;
  return r;
}
__device__ __forceinline__ h8 to_h8v(f32x4 a, f32x4 b){
  h8 r;
  #pragma unroll
  for(int j=0;j<4;j++){ r[j]=(_Float16)a[j]; r[4+j]=(_Float16)b[j]; }
  return r;
}

// Producer/consumer, spill-free: 384 thr = 4 compute + 2 loader waves, 64 rows,
// grid 512 (2 blocks/CU). Loaders stream x via global_load_lds (HBM->LDS direct,
// ZERO data VGPRs) into a depth-2 f32 ring XB[2][64*512B], source-swizzled
// (csw = col ^ ((row&7)<<4)) so consumer ds_reads are bank-spread. Counted
// s_waitcnt vmcnt(16) (never 0 mid-loop) + RAW s_barrier on loader side keeps
// loads in flight across barriers; consumers use __syncthreads() (vmcnt is
// per-wave, consumer's is empty). Protocol: A(t)=x_t ready; consumers ds_read
// x_t -> regs; B(t)=consumed; loader issues t+2 into slot t&1.
//   Compute waves: r3 structure — A = gate-permuted weights (tile nt, row lr ->
//   gate (lr&3)*20+(lr>>2)+nt*4), B = x/h (col = batch row). C-reg i of lane
//   (lr,lg) = gate type i of unit nt*4+lg -> fp32 gates fully in-register.
//   h 2-term f16 via wave-private HB (stride 33, own-wave, no barrier).
__global__ __launch_bounds__(384, 3) void bilstm_kernel(
    const float* __restrict__ x,
    const float* __restrict__ Wih_f, const float* __restrict__ Whh_f,
    const float* __restrict__ bih_f, const float* __restrict__ bhh_f,
    const float* __restrict__ Wih_b,
    const float* __restrict__ bih_b, const float* __restrict__ bhh_b,
    float* __restrict__ out)
{
  __shared__ __attribute__((aligned(16))) float XB[2][ROWS*128]; // 64 KB f32 ring
  __shared__ u32 HBa[NCW][528];                                  // h exchange

  const int tid  = threadIdx.x;
  const int ww   = tid >> 6;
  const int lane = tid & 63;
  const long b0  = (long)blockIdx.x * ROWS;

  if(ww >= NCW){
    // ================= loader waves (global_load_lds, no data VGPRs) ========
    const int w     = ww - NCW;        // 0,1 -> rows w*32 .. w*32+31
    const int rhalf = lane >> 5;       // row within pair
    const int cseg  = lane & 31;       // 16B segment of the 512B row
    auto issue = [&](int t, int slot){
      #pragma unroll
      for(int i=0;i<16;i++){
        const int r2  = w*32 + 2*i + rhalf;
        const int csw = (cseg*16) ^ ((r2&7)<<4);   // source pre-swizzle
        const float* src = x + (b0 + r2)*(long)(SL*NI) + t*NI + (csw>>2);
        float* dst = &XB[slot][(w*32 + 2*i)*128];  // wave-uniform; HW adds lane*16
        __builtin_amdgcn_global_load_lds(
            (const __attribute__((address_space(1))) void*)src,
            (__attribute__((address_space(3))) void*)dst, 16, 0, 0);
      }
    };
    issue(0,0); issue(1,1);            // 32 outstanding
    #pragma unroll
    for(int t=0;t<SL;t++){
      if(t<SL-1) asm volatile("s_waitcnt vmcnt(16)" ::: "memory"); // x_t landed
      else       asm volatile("s_waitcnt vmcnt(0)"  ::: "memory");
      __builtin_amdgcn_sched_barrier(0);
      __builtin_amdgcn_s_barrier();    // A(t): x_t ready (no vmcnt drain!)
      __builtin_amdgcn_s_barrier();    // B(t): x_t consumed
      __builtin_amdgcn_sched_barrier(0);
      if(t+2<SL) issue(t+2, t&1);      // refill freed slot
      __builtin_amdgcn_sched_barrier(0);
    }
    return;
  }

  // ================= compute waves ================
  const int lr  = lane & 15;
  const int lg  = lane >> 4;
  const int gb  = (lr&3)*20 + (lr>>2);
  const long brow = b0 + ww*16 + lr;
  const int fsw = (lr&7)<<2;           // float-index XOR (matches loader swizzle)
  u32* HB = HBa[ww];

  for(int i=lane;i<528;i+=64) HB[i]=0;

  // W_ih_f fragments (f16), register-resident
  h8 WIH[20];
  #pragma unroll
  for(int p=0;p<20;p++){
    const int nt=p>>2, ks=p&3;
    const float* s = Wih_f + (gb+nt*4)*NI + ks*32 + lg*8;
    WIH[p] = to_h8(*(const float4*)s, *(const float4*)(s+4));
  }
  // W_hh_f fragments (K=20 zero-padded to 32)
  h8 WHH[5];
  #pragma unroll
  for(int nt=0;nt<5;nt++){
    h8 r;
    #pragma unroll
    for(int j=0;j<8;j++){
      const int k = lg*8+j;
      r[j] = (_Float16)((k<20) ? Whh_f[(gb+nt*4)*20+k] : 0.f);
    }
    WHH[nt]=r;
  }
  // forward bias, packed f16
  h4 bp[5];
  #pragma unroll
  for(int nt=0;nt<5;nt++)
    #pragma unroll
    for(int ty=0;ty<4;ty++)
      bp[nt][ty] = (_Float16)(bih_f[ty*20+nt*4+lg] + bhh_f[ty*20+nt*4+lg]);

  float cst[5]={0.f,0.f,0.f,0.f,0.f};
  h8 bx[4];
  f32x4 acc[5];

  #pragma unroll
  for(int t=0;t<SL;t++){
    __syncthreads();                   // A(t): slot t&1 holds x_t
    {
      const float* rb = &XB[t&1][(ww*16+lr)*128];
      #pragma unroll
      for(int ks=0;ks<4;ks++){
        f32x4 pa = *(const f32x4*)(rb + ((ks*32+lg*8)   ^ fsw));
        f32x4 pb = *(const f32x4*)(rb + ((ks*32+lg*8+4) ^ fsw));
        bx[ks] = to_h8v(pa, pb);
      }
    }
    __syncthreads();                   // B(t): consumed (lgkm drained by sync)
    // h_{t-1} read (own-wave LDS, no barrier)
    u32x4 hb0, hb1;
    if(t>0){
      const u32* hp = HB + lr*33 + lg*8;
      hb0=*(const u32x4*)hp; hb1=*(const u32x4*)(hp+4);
    }
    #pragma unroll
    for(int nt=0;nt<5;nt++){
      acc[nt][0]=(float)bp[nt][0]; acc[nt][1]=(float)bp[nt][1];
      acc[nt][2]=(float)bp[nt][2]; acc[nt][3]=(float)bp[nt][3];
    }
    // projection: 20 MFMAs
    #pragma unroll
    for(int ks=0;ks<4;ks++)
      #pragma unroll
      for(int nt=0;nt<5;nt++)
        acc[nt]=MFH(WIH[nt*4+ks], bx[ks], acc[nt]);
    // recurrence: 10 MFMAs (h 2-term f16)
    if(t>0){
      u32x4 hh, hl;
      hh[0]=(hb0[0]>>16)|(hb0[1]&0xffff0000u);
      hh[1]=(hb0[2]>>16)|(hb0[3]&0xffff0000u);
      hh[2]=(hb1[0]>>16)|(hb1[1]&0xffff0000u);
      hh[3]=(hb1[2]>>16)|(hb1[3]&0xffff0000u);
      hl[0]=(hb0[0]&0xffffu)|(hb0[1]<<16);
      hl[1]=(hb0[2]&0xffffu)|(hb0[3]<<16);
      hl[2]=(hb1[0]&0xffffu)|(hb1[1]<<16);
      hl[3]=(hb1[2]&0xffffu)|(hb1[3]<<16);
      h8 fh=__builtin_bit_cast(h8,hh), fl=__builtin_bit_cast(h8,hl);
      #pragma unroll
      for(int nt=0;nt<5;nt++){
        acc[nt]=MFH(WHH[nt], fh, acc[nt]);
        acc[nt]=MFH(WHH[nt], fl, acc[nt]);
      }
    }
    // in-register fp32 gate math
    #pragma unroll
    for(int nt=0;nt<5;nt++){
      float ig=sigf(acc[nt][0]);
      float fg=sigf(acc[nt][1]);
      float gg=tanhf2(acc[nt][2]);
      float og=sigf(acc[nt][3]);
      cst[nt]=fg*cst[nt]+ig*gg;
      float hv=og*tanhf2(cst[nt]);
      if(t==SL-1){
        out[brow*40 + nt*4+lg] = hv;
      } else {
        _Float16 hh16=(_Float16)hv;
        _Float16 hl16=(_Float16)(hv-(float)hh16);
        HB[lr*33 + nt*4+lg] = ((u32)__builtin_bit_cast(unsigned short,hh16)<<16)
                              | (u32)__builtin_bit_cast(unsigned short,hl16);
      }
    }
  }

  // ---- backward direction: one step, h0=c0=0; bx still holds x_9 frags ----
  f32x4 a2[5];
  #pragma unroll
  for(int nt=0;nt<5;nt++)
    #pragma unroll
    for(int ty=0;ty<4;ty++)
      a2[nt][ty] = bih_b[ty*20+nt*4+lg] + bhh_b[ty*20+nt*4+lg];
  #pragma unroll
  for(int ks=0;ks<4;ks++){
    #pragma unroll
    for(int nt=0;nt<5;nt++){
      const float* s = Wih_b + (gb+nt*4)*NI + ks*32 + lg*8;
      a2[nt]=MFH(to_h8(*(const float4*)s, *(const float4*)(s+4)), bx[ks], a2[nt]);
    }
  }
  #pragma unroll
  for(int nt=0;nt<5;nt++){
    float ig=sigf(a2[nt][0]);
    float gg=tanhf2(a2[nt][2]);
    float og=sigf(a2[nt][3]);
    out[brow*40 + 20 + nt*4+lg] = og*tanhf2(ig*gg);   // c = i*g (f-gate hits c0=0)
  }
}

extern "C" void kernel_launch(void* const* d_in, const int* in_sizes, int n_in,
                              void* d_out, int out_size, void* d_ws, size_t ws_size,
                              hipStream_t stream) {
  const float* x     = (const float*)d_in[0];
  const float* Wih_f = (const float*)d_in[1];
  const float* Whh_f = (const float*)d_in[2];
  const float* bih_f = (const float*)d_in[3];
  const float* bhh_f = (const float*)d_in[4];
  const float* Wih_b = (const float*)d_in[5];
  // d_in[6] = W_hh_b: provably unused (hs_b[0] has h0 = 0)
  const float* bih_b = (const float*)d_in[7];
  const float* bhh_b = (const float*)d_in[8];
  float* out = (float*)d_out;
  bilstm_kernel<<<dim3(512), dim3(384), 0, stream>>>(
      x, Wih_f, Whh_f, bih_f, bhh_f, Wih_b, bih_b, bhh_b, out);
}

// Round 9
// 94.699 us; speedup vs baseline: 1.6714x; 1.1935x over previous
//
#include <hip/hip_runtime.h>

#define SL 10
#define NI 128

typedef float f32x4 __attribute__((ext_vector_type(4)));
typedef unsigned int u32;
typedef u32 u32x4 __attribute__((ext_vector_type(4)));
typedef _Float16 h8 __attribute__((ext_vector_type(8)));
typedef _Float16 h4 __attribute__((ext_vector_type(4)));

__device__ __forceinline__ f32x4 MFH(h8 a, h8 b, f32x4 c){
  return __builtin_amdgcn_mfma_f32_16x16x32_f16(a, b, c, 0, 0, 0);
}
__device__ __forceinline__ float sigf(float x){ return __fdividef(1.f, 1.f + __expf(-x)); }
__device__ __forceinline__ float tanhf2(float x){ return __fdividef(2.f, 1.f + __expf(-2.f*x)) - 1.f; }

__device__ __forceinline__ h8 to_h8(float4 a, float4 b){
  h8 r;
  r[0]=(_Float16)a.x; r[1]=(_Float16)a.y; r[2]=(_Float16)a.z; r[3]=(_Float16)a.w;
  r[4]=(_Float16)b.x; r[5]=(_Float16)b.y; r[6]=(_Float16)b.z; r[7]=(_Float16)b.w;
  return r;
}

// Phase-split: one wave (64 thr) per 16 batch rows, zero barriers.
// PHASE 1 (pure stream): the wave's ENTIRE x panel (16 rows x 10 t x 512B) is
//   loaded with 1KB-contiguous spans (instr j covers rows {2j,2j+1}; lane =
//   row 2j+rh, float4 kq), f32->f16, ds_write into a 40KB swizzled LDS panel.
//   2-deep ping-pong (8+8 float4), nothing else in the phase -> fill-kernel-like
//   duty cycle; all global latency concentrated here.
// PHASE 2 (pure compute): 10 steps of ds_read_b128 -> 30 MFMA -> in-register
//   fp32 gates; NO global traffic. h 2-term f16 via wave-private HB (stride 33,
//   in-order DS pipe, no barrier).
//   A = gate-permuted weights (tile nt, A-row lr -> gate (lr&3)*20+(lr>>2)+nt*4),
//   B = x/h (col = batch row lr); C-reg i of lane (lr,lg) = gate type i of unit
//   nt*4+lg -> gates fully in-register. Backward dir: 1 step from bx (=x_9).
// NO __launch_bounds__ occupancy arg (r7/r8: it clamps VGPR -> scratch spill).
__global__ __launch_bounds__(64) void bilstm_kernel(
    const float* __restrict__ x,
    const float* __restrict__ Wih_f, const float* __restrict__ Whh_f,
    const float* __restrict__ bih_f, const float* __restrict__ bhh_f,
    const float* __restrict__ Wih_b,
    const float* __restrict__ bih_b, const float* __restrict__ bhh_b,
    float* __restrict__ out)
{
  __shared__ __attribute__((aligned(16))) char XS[SL*4096]; // [t][row16][256B f16, xor-swz]
  __shared__ u32 HB[528];                                   // h exchange, stride 33

  const int l  = threadIdx.x;
  const int lr = l & 15;
  const int lg = l >> 4;
  const int rh = l >> 5;        // row within a 1KB pair-span
  const int kq = l & 31;        // float4 index within the 512B row
  const long b0 = (long)blockIdx.x * 16;
  const int gb = (lr&3)*20 + (lr>>2);

  for(int i=l;i<528;i+=64) HB[i]=0;

  // ================= PHASE 1: stream the whole x panel into LDS ============
  const float* xsrc = x + (b0 + rh)*(long)(SL*NI) + kq*4;
  const int wr   = 2*0 + rh;                       // recomputed per j below
  float4 pb0[8], pb1[8];
  #pragma unroll
  for(int j=0;j<8;j++) pb0[j] = *(const float4*)(xsrc + (long)2*j*SL*NI);       // t=0
  #pragma unroll
  for(int j=0;j<8;j++) pb1[j] = *(const float4*)(xsrc + NI + (long)2*j*SL*NI);  // t=1
  #pragma unroll
  for(int t=0;t<SL;t++){
    #pragma unroll
    for(int j=0;j<8;j++){
      float4 v = (t&1) ? pb1[j] : pb0[j];
      h4 hv; hv[0]=(_Float16)v.x; hv[1]=(_Float16)v.y; hv[2]=(_Float16)v.z; hv[3]=(_Float16)v.w;
      const int r = 2*j + rh;
      *(h4*)(XS + t*4096 + r*256 + ((kq*8) ^ ((r&7)<<4))) = hv;
    }
    if(t+2<SL){
      #pragma unroll
      for(int j=0;j<8;j++){
        float4 ld = *(const float4*)(xsrc + (t+2)*NI + (long)2*j*SL*NI);
        if(t&1) pb1[j]=ld; else pb0[j]=ld;
      }
    }
  }
  (void)wr;

  // ================= weights (loaded after x buffers are dead) =============
  h8 WIH[20];
  #pragma unroll
  for(int p=0;p<20;p++){
    const int nt=p>>2, ks=p&3;
    const float* s = Wih_f + (gb+nt*4)*NI + ks*32 + lg*8;
    WIH[p] = to_h8(*(const float4*)s, *(const float4*)(s+4));
  }
  h8 WHH[5];
  #pragma unroll
  for(int nt=0;nt<5;nt++){
    h8 r;
    #pragma unroll
    for(int j=0;j<8;j++){
      const int k = lg*8+j;
      r[j] = (_Float16)((k<20) ? Whh_f[(gb+nt*4)*20+k] : 0.f);
    }
    WHH[nt]=r;
  }
  h4 bp[5];
  #pragma unroll
  for(int nt=0;nt<5;nt++)
    #pragma unroll
    for(int ty=0;ty<4;ty++)
      bp[nt][ty] = (_Float16)(bih_f[ty*20+nt*4+lg] + bhh_f[ty*20+nt*4+lg]);

  // ================= PHASE 2: pure compute, no global traffic ==============
  const int rsw = (lr&7)<<4;
  float cst[5]={0.f,0.f,0.f,0.f,0.f};
  h8 bx[4];
  f32x4 acc[5];

  #pragma unroll
  for(int t=0;t<SL;t++){
    const char* rb = XS + t*4096 + lr*256;
    #pragma unroll
    for(int ks=0;ks<4;ks++)
      bx[ks] = *(const h8*)(rb + ((ks*64 + lg*16) ^ rsw));
    u32x4 hb0, hb1;
    if(t>0){
      const u32* hp = HB + lr*33 + lg*8;
      hb0=*(const u32x4*)hp; hb1=*(const u32x4*)(hp+4);
    }
    #pragma unroll
    for(int nt=0;nt<5;nt++){
      acc[nt][0]=(float)bp[nt][0]; acc[nt][1]=(float)bp[nt][1];
      acc[nt][2]=(float)bp[nt][2]; acc[nt][3]=(float)bp[nt][3];
    }
    // projection: 20 MFMAs
    #pragma unroll
    for(int ks=0;ks<4;ks++)
      #pragma unroll
      for(int nt=0;nt<5;nt++)
        acc[nt]=MFH(WIH[nt*4+ks], bx[ks], acc[nt]);
    // recurrence: 10 MFMAs (h 2-term f16)
    if(t>0){
      u32x4 hh, hl;
      hh[0]=(hb0[0]>>16)|(hb0[1]&0xffff0000u);
      hh[1]=(hb0[2]>>16)|(hb0[3]&0xffff0000u);
      hh[2]=(hb1[0]>>16)|(hb1[1]&0xffff0000u);
      hh[3]=(hb1[2]>>16)|(hb1[3]&0xffff0000u);
      hl[0]=(hb0[0]&0xffffu)|(hb0[1]<<16);
      hl[1]=(hb0[2]&0xffffu)|(hb0[3]<<16);
      hl[2]=(hb1[0]&0xffffu)|(hb1[1]<<16);
      hl[3]=(hb1[2]&0xffffu)|(hb1[3]<<16);
      h8 fh=__builtin_bit_cast(h8,hh), fl=__builtin_bit_cast(h8,hl);
      #pragma unroll
      for(int nt=0;nt<5;nt++){
        acc[nt]=MFH(WHH[nt], fh, acc[nt]);
        acc[nt]=MFH(WHH[nt], fl, acc[nt]);
      }
    }
    // in-register fp32 gate math
    #pragma unroll
    for(int nt=0;nt<5;nt++){
      float ig=sigf(acc[nt][0]);
      float fg=sigf(acc[nt][1]);
      float gg=tanhf2(acc[nt][2]);
      float og=sigf(acc[nt][3]);
      cst[nt]=fg*cst[nt]+ig*gg;
      float hv=og*tanhf2(cst[nt]);
      if(t==SL-1){
        out[(b0+lr)*40 + nt*4+lg] = hv;
      } else {
        _Float16 hh16=(_Float16)hv;
        _Float16 hl16=(_Float16)(hv-(float)hh16);
        HB[lr*33 + nt*4+lg] = ((u32)__builtin_bit_cast(unsigned short,hh16)<<16)
                              | (u32)__builtin_bit_cast(unsigned short,hl16);
      }
    }
  }

  // ---- backward direction: one step, h0=c0=0; bx still holds x_9 frags ----
  f32x4 a2[5];
  #pragma unroll
  for(int nt=0;nt<5;nt++)
    #pragma unroll
    for(int ty=0;ty<4;ty++)
      a2[nt][ty] = bih_b[ty*20+nt*4+lg] + bhh_b[ty*20+nt*4+lg];
  #pragma unroll
  for(int ks=0;ks<4;ks++){
    #pragma unroll
    for(int nt=0;nt<5;nt++){
      const float* s = Wih_b + (gb+nt*4)*NI + ks*32 + lg*8;
      a2[nt]=MFH(to_h8(*(const float4*)s, *(const float4*)(s+4)), bx[ks], a2[nt]);
    }
  }
  #pragma unroll
  for(int nt=0;nt<5;nt++){
    float ig=sigf(a2[nt][0]);
    float gg=tanhf2(a2[nt][2]);
    float og=tanhf2(ig*gg);            // placeholder to keep names aligned
    // recompute properly below (avoid accidental reuse)
    float ogate=sigf(a2[nt][3]);
    out[(b0+lr)*40 + 20 + nt*4+lg] = ogate*og;   // c = i*g; h = sig(o)*tanh(c)
  }
}

extern "C" void kernel_launch(void* const* d_in, const int* in_sizes, int n_in,
                              void* d_out, int out_size, void* d_ws, size_t ws_size,
                              hipStream_t stream) {
  const float* x     = (const float*)d_in[0];
  const float* Wih_f = (const float*)d_in[1];
  const float* Whh_f = (const float*)d_in[2];
  const float* bih_f = (const float*)d_in[3];
  const float* bhh_f = (const float*)d_in[4];
  const float* Wih_b = (const float*)d_in[5];
  // d_in[6] = W_hh_b: provably unused (hs_b[0] has h0 = 0)
  const float* bih_b = (const float*)d_in[7];
  const float* bhh_b = (const float*)d_in[8];
  float* out = (float*)d_out;
  bilstm_kernel<<<dim3(2048), dim3(64), 0, stream>>>(
      x, Wih_f, Whh_f, bih_f, bhh_f, Wih_b, bih_b, bhh_b, out);
}

// Round 10
// 80.277 us; speedup vs baseline: 1.9717x; 1.1797x over previous
//
#include <hip/hip_runtime.h>

#define SL 10
#define NI 128

typedef float f32x4 __attribute__((ext_vector_type(4)));
typedef unsigned int u32;
typedef u32 u32x4 __attribute__((ext_vector_type(4)));
typedef _Float16 h8 __attribute__((ext_vector_type(8)));
typedef _Float16 h4 __attribute__((ext_vector_type(4)));

__device__ __forceinline__ f32x4 MFH(h8 a, h8 b, f32x4 c){
  return __builtin_amdgcn_mfma_f32_16x16x32_f16(a, b, c, 0, 0, 0);
}
__device__ __forceinline__ float sigf(float x){ return __fdividef(1.f, 1.f + __expf(-x)); }
__device__ __forceinline__ float tanhf2(float x){ return __fdividef(2.f, 1.f + __expf(-2.f*x)) - 1.f; }

__device__ __forceinline__ h8 to_h8(float4 a, float4 b){
  h8 r;
  r[0]=(_Float16)a.x; r[1]=(_Float16)a.y; r[2]=(_Float16)a.z; r[3]=(_Float16)a.w;
  r[4]=(_Float16)b.x; r[5]=(_Float16)b.y; r[6]=(_Float16)b.z; r[7]=(_Float16)b.w;
  return r;
}

// K-SPLIT r3: 2 waves per 16 batch rows (wave kh owns x columns kh*64..kh*64+63)
// -> 4096 waves = 16 waves/CU (vs 8 in r3-r6): tests/exploits the r9 finding
// that delivered load BW scales with per-CU wave-stream concurrency.
//   Per wave/step: 10 proj MFMAs (its K-half) -> partial pre-acts exchanged via
//   5KB LDS (PX); wave0 finalizes tiles 0-2 (recurrence + gates + h), wave1
//   tiles 3-4. h shared via HB (stride 33). 2 __syncthreads per step.
//   A = gate-permuted weights (tile nt, A-row lr -> gate (lr&3)*20+(lr>>2)+nt*4),
//   B = x/h (col = batch row lr); C-reg i of lane (lr,lg) = gate type i of
//   unit nt*4+lg -> gates fully in-register. h 2-term f16; x/W 1-term f16.
// __launch_bounds__(128,4): VGPR cap 128 = 4 waves/SIMD. Registers trimmed to
// fit (backward weights overwrite WIH; per-wave WHH subset; cst split).
__global__ __launch_bounds__(128, 4) void bilstm_kernel(
    const float* __restrict__ x,
    const float* __restrict__ Wih_f, const float* __restrict__ Whh_f,
    const float* __restrict__ bih_f, const float* __restrict__ bhh_f,
    const float* __restrict__ Wih_b,
    const float* __restrict__ bih_b, const float* __restrict__ bhh_b,
    float* __restrict__ out)
{
  __shared__ __attribute__((aligned(16))) f32x4 PX1[64*3]; // wave1 partials nt0-2
  __shared__ __attribute__((aligned(16))) f32x4 PX0[64*2]; // wave0 partials nt3-4
  __shared__ u32 HB[528];                                  // h exchange, stride 33

  const int tid  = threadIdx.x;
  const int kh   = tid >> 6;          // K-half owner (wave id)
  const int lane = tid & 63;
  const int lr = lane & 15;
  const int lg = lane >> 4;
  const long b0 = (long)blockIdx.x * 16;
  const int gb = (lr&3)*20 + (lr>>2);

  for(int i=tid;i<528;i+=128) HB[i]=0;

  // W_ih_f fragments for this wave's K-half (10 frags)
  h8 WIH[10];
  #pragma unroll
  for(int p=0;p<10;p++){
    const int nt=p>>1, ks=p&1;
    const float* s = Wih_f + (gb+nt*4)*NI + kh*64 + ks*32 + lg*8;
    WIH[p] = to_h8(*(const float4*)s, *(const float4*)(s+4));
  }
  // W_hh frags for owned tiles: wave0 -> nt {0,1,2}; wave1 -> nt {3,4} (+dup 4)
  h8 WHH[3];
  #pragma unroll
  for(int i=0;i<3;i++){
    const int nt = kh ? (i<2 ? 3+i : 4) : i;
    h8 r;
    #pragma unroll
    for(int j=0;j<8;j++){
      const int k = lg*8+j;
      r[j] = (_Float16)((k<20) ? Whh_f[(gb+nt*4)*20+k] : 0.f);
    }
    WHH[i]=r;
  }
  // forward bias (seeded into wave0's partial only, so the sum carries it once)
  h4 bp[5];
  #pragma unroll
  for(int nt=0;nt<5;nt++)
    #pragma unroll
    for(int ty=0;ty<4;ty++)
      bp[nt][ty] = kh ? (_Float16)0.f
                      : (_Float16)(bih_f[ty*20+nt*4+lg] + bhh_f[ty*20+nt*4+lg]);

  // x fragment source for this wave's K-half
  const float* xb = x + (b0+lr)*(long)(SL*NI) + kh*64 + lg*8;
  float4 xa0,xc0,xa1,xc1;
  xa0=*(const float4*)(xb);    xc0=*(const float4*)(xb+4);
  xa1=*(const float4*)(xb+32); xc1=*(const float4*)(xb+36);

  float cstA=0.f, cstB=0.f, cstC=0.f;    // wave0: nt0,1,2 ; wave1: nt3,4 (A,B)
  h8 bx0, bx1;
  f32x4 acc[5];

  #pragma unroll
  for(int t=0;t<SL;t++){
    bx0 = to_h8(xa0,xc0); bx1 = to_h8(xa1,xc1);
    if(t+1<SL){
      const float* p = xb + (t+1)*NI;
      xa0=*(const float4*)(p);    xc0=*(const float4*)(p+4);
      xa1=*(const float4*)(p+32); xc1=*(const float4*)(p+36);
    }
    #pragma unroll
    for(int nt=0;nt<5;nt++){
      acc[nt][0]=(float)bp[nt][0]; acc[nt][1]=(float)bp[nt][1];
      acc[nt][2]=(float)bp[nt][2]; acc[nt][3]=(float)bp[nt][3];
    }
    // projection partials: 10 MFMAs (this K-half)
    #pragma unroll
    for(int nt=0;nt<5;nt++){
      acc[nt]=MFH(WIH[nt*2+0], bx0, acc[nt]);
      acc[nt]=MFH(WIH[nt*2+1], bx1, acc[nt]);
    }
    // exchange partials for non-owned tiles
    if(kh){ PX1[lane*3+0]=acc[0]; PX1[lane*3+1]=acc[1]; PX1[lane*3+2]=acc[2]; }
    else  { PX0[lane*2+0]=acc[3]; PX0[lane*2+1]=acc[4]; }
    __syncthreads();                                   // bar1: partials visible
    // h_{t-1} fragments (shared HB)
    h8 fh, fl;
    if(t>0){
      const u32* hp = HB + lr*33 + lg*8;
      u32x4 hb0=*(const u32x4*)hp, hb1=*(const u32x4*)(hp+4);
      u32x4 hhv, hlv;
      hhv[0]=(hb0[0]>>16)|(hb0[1]&0xffff0000u);
      hhv[1]=(hb0[2]>>16)|(hb0[3]&0xffff0000u);
      hhv[2]=(hb1[0]>>16)|(hb1[1]&0xffff0000u);
      hhv[3]=(hb1[2]>>16)|(hb1[3]&0xffff0000u);
      hlv[0]=(hb0[0]&0xffffu)|(hb0[1]<<16);
      hlv[1]=(hb0[2]&0xffffu)|(hb0[3]<<16);
      hlv[2]=(hb1[0]&0xffffu)|(hb1[1]<<16);
      hlv[3]=(hb1[2]&0xffffu)|(hb1[3]<<16);
      fh=__builtin_bit_cast(h8,hhv); fl=__builtin_bit_cast(h8,hlv);
    }
    if(kh==0){
      // finalize tiles 0-2
      acc[0]+=PX1[lane*3+0]; acc[1]+=PX1[lane*3+1]; acc[2]+=PX1[lane*3+2];
      if(t>0){
        #pragma unroll
        for(int i=0;i<3;i++){
          acc[i]=MFH(WHH[i], fh, acc[i]);
          acc[i]=MFH(WHH[i], fl, acc[i]);
        }
      }
      #pragma unroll
      for(int i=0;i<3;i++){
        float ig=sigf(acc[i][0]);
        float fg=sigf(acc[i][1]);
        float gg=tanhf2(acc[i][2]);
        float og=sigf(acc[i][3]);
        float& cs = (i==0)?cstA:((i==1)?cstB:cstC);
        cs = fg*cs + ig*gg;
        float hv = og*tanhf2(cs);
        if(t==SL-1){
          out[(b0+lr)*40 + i*4+lg] = hv;
        } else {
          _Float16 hh16=(_Float16)hv;
          _Float16 hl16=(_Float16)(hv-(float)hh16);
          HB[lr*33 + i*4+lg] = ((u32)__builtin_bit_cast(unsigned short,hh16)<<16)
                               | (u32)__builtin_bit_cast(unsigned short,hl16);
        }
      }
    } else {
      // finalize tiles 3-4
      acc[3]+=PX0[lane*2+0]; acc[4]+=PX0[lane*2+1];
      if(t>0){
        #pragma unroll
        for(int i=0;i<2;i++){
          acc[3+i]=MFH(WHH[i], fh, acc[3+i]);
          acc[3+i]=MFH(WHH[i], fl, acc[3+i]);
        }
      }
      #pragma unroll
      for(int i=0;i<2;i++){
        float ig=sigf(acc[3+i][0]);
        float fg=sigf(acc[3+i][1]);
        float gg=tanhf2(acc[3+i][2]);
        float og=sigf(acc[3+i][3]);
        float& cs = (i==0)?cstA:cstB;
        cs = fg*cs + ig*gg;
        float hv = og*tanhf2(cs);
        if(t==SL-1){
          out[(b0+lr)*40 + (3+i)*4+lg] = hv;
        } else {
          _Float16 hh16=(_Float16)hv;
          _Float16 hl16=(_Float16)(hv-(float)hh16);
          HB[lr*33 + (3+i)*4+lg] = ((u32)__builtin_bit_cast(unsigned short,hh16)<<16)
                                   | (u32)__builtin_bit_cast(unsigned short,hl16);
        }
      }
    }
    __syncthreads();                                   // bar2: h complete
  }

  // ---------------- backward direction: one step, h0=c0=0 -------------------
  // overwrite WIH with W_ih_b frags (register reuse); bx0/bx1 still hold x_9
  #pragma unroll
  for(int p=0;p<10;p++){
    const int nt=p>>1, ks=p&1;
    const float* s = Wih_b + (gb+nt*4)*NI + kh*64 + ks*32 + lg*8;
    WIH[p] = to_h8(*(const float4*)s, *(const float4*)(s+4));
  }
  f32x4 a2[5];
  #pragma unroll
  for(int nt=0;nt<5;nt++){ f32x4 z={0.f,0.f,0.f,0.f}; a2[nt]=z; }
  #pragma unroll
  for(int nt=0;nt<5;nt++){
    a2[nt]=MFH(WIH[nt*2+0], bx0, a2[nt]);
    a2[nt]=MFH(WIH[nt*2+1], bx1, a2[nt]);
  }
  if(kh){ PX1[lane*3+0]=a2[0]; PX1[lane*3+1]=a2[1]; PX1[lane*3+2]=a2[2]; }
  else  { PX0[lane*2+0]=a2[3]; PX0[lane*2+1]=a2[4]; }
  __syncthreads();
  if(kh==0){
    #pragma unroll
    for(int i=0;i<3;i++){
      f32x4 v = a2[i] + PX1[lane*3+i];
      const int u = i*4+lg;
      float ig=sigf(v[0] + bih_b[u]       + bhh_b[u]);
      float gg=tanhf2(v[2] + bih_b[40+u]  + bhh_b[40+u]);
      float og=sigf(v[3] + bih_b[60+u]    + bhh_b[60+u]);
      out[(b0+lr)*40 + 20 + u] = og*tanhf2(ig*gg);   // c = i*g (f-gate hits c0=0)
    }
  } else {
    #pragma unroll
    for(int i=0;i<2;i++){
      f32x4 v = a2[3+i] + PX0[lane*2+i];
      const int u = (3+i)*4+lg;
      float ig=sigf(v[0] + bih_b[u]       + bhh_b[u]);
      float gg=tanhf2(v[2] + bih_b[40+u]  + bhh_b[40+u]);
      float og=sigf(v[3] + bih_b[60+u]    + bhh_b[60+u]);
      out[(b0+lr)*40 + 20 + u] = og*tanhf2(ig*gg);
    }
  }
}

extern "C" void kernel_launch(void* const* d_in, const int* in_sizes, int n_in,
                              void* d_out, int out_size, void* d_ws, size_t ws_size,
                              hipStream_t stream) {
  const float* x     = (const float*)d_in[0];
  const float* Wih_f = (const float*)d_in[1];
  const float* Whh_f = (const float*)d_in[2];
  const float* bih_f = (const float*)d_in[3];
  const float* bhh_f = (const float*)d_in[4];
  const float* Wih_b = (const float*)d_in[5];
  // d_in[6] = W_hh_b: provably unused (hs_b[0] has h0 = 0)
  const float* bih_b = (const float*)d_in[7];
  const float* bhh_b = (const float*)d_in[8];
  float* out = (float*)d_out;
  bilstm_kernel<<<dim3(2048), dim3(128), 0, stream>>>(
      x, Wih_f, Whh_f, bih_f, bhh_f, Wih_b, bih_b, bhh_b, out);
}